// Round 1
// baseline (521.300 us; speedup 1.0000x reference)
//
#include <hip/hip_runtime.h>

// InteractLayer: B=16384 batches of 2-head attention, F=32 tokens, D=64 in-dim,
// H=64 out-dim (2 heads x 32), fp32 everywhere. Round 0: correct fp32 baseline,
// register-tiled projections, LDS-staged activations, W from global (L1-hot).

constexpr int kF  = 32;   // tokens per batch
constexpr int kD  = 64;   // input feature dim
constexpr int kH  = 64;   // projected dim (heads * att)
constexpr int kNH = 2;    // heads
constexpr int kAS = 32;   // att size per head

// LDS row strides (floats), padded for bank-conflict avoidance
constexpr int XS = 68;    // s_x rows (multiple of 4 -> b128-aligned reads)
constexpr int QS = 66;    // s_qkvr rows (even -> float2-aligned, conflict-free ph2/3)
constexpr int SS = 33;    // s_scores rows (odd -> conflict-free softmax row access)

__global__ __launch_bounds__(256)
void interact_kernel(const float* __restrict__ X,
                     const float* __restrict__ Wq, const float* __restrict__ Wk,
                     const float* __restrict__ Wv, const float* __restrict__ Wr,
                     float* __restrict__ out)
{
    __shared__ float s_x[kF * XS];          // 2176 f = 8704 B
    __shared__ float s_qkvr[4 * kF * QS];   // 8448 f = 33792 B  (Q,K,V,R)
    __shared__ float s_s[kNH * kF * SS];    // 2112 f = 8448 B   (scores)

    const int t = threadIdx.x;
    const int b = blockIdx.x;
    const float* __restrict__ Xb = X + (size_t)b * (kF * kD);

    // ---- stage X (32x64) into LDS, padded stride ----
    #pragma unroll
    for (int i = 0; i < 2; ++i) {
        int idx = i * 256 + t;              // 0..511 float4s
        int f = idx >> 4;
        int c = idx & 15;
        float4 v = reinterpret_cast<const float4*>(Xb)[idx];
        *reinterpret_cast<float4*>(&s_x[f * XS + c * 4]) = v;
    }
    __syncthreads();

    // ---- phase 1: Q,K,V,R projections. wave = matrix; thread tile = 4f x 8e ----
    {
        const int mat  = t >> 6;            // wave id 0..3
        const int lane = t & 63;
        const int fb   = (lane >> 3) << 2;  // 0,4,...,28
        const int eb   = (lane & 7) << 3;   // 0,8,...,56
        const float* __restrict__ W =
            (mat == 0) ? Wq : (mat == 1) ? Wk : (mat == 2) ? Wv : Wr;

        float acc[4][8];
        #pragma unroll
        for (int ff = 0; ff < 4; ++ff)
            #pragma unroll
            for (int j = 0; j < 8; ++j) acc[ff][j] = 0.0f;

        for (int dc = 0; dc < 16; ++dc) {   // 4 d's per chunk
            float w[4][8];
            #pragma unroll
            for (int dd = 0; dd < 4; ++dd) {
                const float* wp = W + (dc * 4 + dd) * kH + eb;
                const float4 a = *reinterpret_cast<const float4*>(wp);
                const float4 c = *reinterpret_cast<const float4*>(wp + 4);
                w[dd][0] = a.x; w[dd][1] = a.y; w[dd][2] = a.z; w[dd][3] = a.w;
                w[dd][4] = c.x; w[dd][5] = c.y; w[dd][6] = c.z; w[dd][7] = c.w;
            }
            #pragma unroll
            for (int ff = 0; ff < 4; ++ff) {
                const float4 xv =
                    *reinterpret_cast<const float4*>(&s_x[(fb + ff) * XS + dc * 4]);
                const float xs[4] = {xv.x, xv.y, xv.z, xv.w};
                #pragma unroll
                for (int dd = 0; dd < 4; ++dd)
                    #pragma unroll
                    for (int j = 0; j < 8; ++j)
                        acc[ff][j] = fmaf(xs[dd], w[dd][j], acc[ff][j]);
            }
        }
        #pragma unroll
        for (int ff = 0; ff < 4; ++ff)
            #pragma unroll
            for (int j = 0; j < 8; ++j)
                s_qkvr[(mat * kF + fb + ff) * QS + eb + j] = acc[ff][j];
    }
    __syncthreads();

    // ---- phase 2: scores S[h][q][k] = Q[q] . K[k] (per head) ----
    {
        const int r  = t >> 2;              // score row 0..63 -> (h,q)
        const int h  = r >> 5;
        const int q  = r & 31;
        const int kb = (t & 3) * 8;         // this thread's 8 k's

        const float* __restrict__ Qp = &s_qkvr[(0 * kF + q) * QS + h * kAS];
        float qreg[32];
        #pragma unroll
        for (int aa = 0; aa < 16; ++aa) {
            float2 qv = *reinterpret_cast<const float2*>(Qp + aa * 2);
            qreg[2 * aa] = qv.x; qreg[2 * aa + 1] = qv.y;
        }
        float acc[8];
        #pragma unroll
        for (int kk = 0; kk < 8; ++kk) acc[kk] = 0.0f;
        #pragma unroll
        for (int kk = 0; kk < 8; ++kk) {
            const float* __restrict__ Kp =
                &s_qkvr[(1 * kF + kb + kk) * QS + h * kAS];
            #pragma unroll
            for (int aa = 0; aa < 16; ++aa) {
                float2 kv = *reinterpret_cast<const float2*>(Kp + aa * 2);
                acc[kk] = fmaf(qreg[2 * aa], kv.x, acc[kk]);
                acc[kk] = fmaf(qreg[2 * aa + 1], kv.y, acc[kk]);
            }
        }
        #pragma unroll
        for (int kk = 0; kk < 8; ++kk)
            s_s[r * SS + kb + kk] = acc[kk];
    }
    __syncthreads();

    // ---- softmax over k for each of 64 (h,q) rows; wave 0 only ----
    if (t < 64) {
        float* row = &s_s[t * SS];
        float m = row[0];
        #pragma unroll
        for (int c = 1; c < 32; ++c) m = fmaxf(m, row[c]);
        float sum = 0.0f;
        #pragma unroll
        for (int c = 0; c < 32; ++c) {
            float e = __expf(row[c] - m);
            row[c] = e;
            sum += e;
        }
        const float inv = 1.0f / sum;
        #pragma unroll
        for (int c = 0; c < 32; ++c) row[c] *= inv;
    }
    __syncthreads();

    // ---- phase 3: out[f][e] = sum_k P[h][f][k] * V[k][e]  (+R, relu) ----
    {
        const int f  = t >> 3;              // 0..31
        const int eb = (t & 7) * 8;         // 0..56
        const int h  = eb >> 5;             // head of this e-slice

        const float* __restrict__ Sp = &s_s[(h * kF + f) * SS];
        float acc[8];
        #pragma unroll
        for (int j = 0; j < 8; ++j) acc[j] = 0.0f;

        #pragma unroll
        for (int k = 0; k < 32; ++k) {
            const float p = Sp[k];
            const float* __restrict__ Vp = &s_qkvr[(2 * kF + k) * QS + eb];
            #pragma unroll
            for (int j = 0; j < 4; ++j) {
                float2 vv = *reinterpret_cast<const float2*>(Vp + j * 2);
                acc[2 * j]     = fmaf(p, vv.x, acc[2 * j]);
                acc[2 * j + 1] = fmaf(p, vv.y, acc[2 * j + 1]);
            }
        }

        const float* __restrict__ Rp = &s_qkvr[(3 * kF + f) * QS + eb];
        float4 o0, o1;
        o0.x = fmaxf(acc[0] + Rp[0], 0.0f);
        o0.y = fmaxf(acc[1] + Rp[1], 0.0f);
        o0.z = fmaxf(acc[2] + Rp[2], 0.0f);
        o0.w = fmaxf(acc[3] + Rp[3], 0.0f);
        o1.x = fmaxf(acc[4] + Rp[4], 0.0f);
        o1.y = fmaxf(acc[5] + Rp[5], 0.0f);
        o1.z = fmaxf(acc[6] + Rp[6], 0.0f);
        o1.w = fmaxf(acc[7] + Rp[7], 0.0f);

        float* __restrict__ Op = out + ((size_t)b * kF + f) * kH + eb;
        *reinterpret_cast<float4*>(Op)     = o0;
        *reinterpret_cast<float4*>(Op + 4) = o1;
    }
}

extern "C" void kernel_launch(void* const* d_in, const int* in_sizes, int n_in,
                              void* d_out, int out_size, void* d_ws, size_t ws_size,
                              hipStream_t stream) {
    const float* X  = (const float*)d_in[0];
    const float* Wq = (const float*)d_in[1];
    const float* Wk = (const float*)d_in[2];
    const float* Wv = (const float*)d_in[3];
    const float* Wr = (const float*)d_in[4];
    float* out = (float*)d_out;

    const int B = in_sizes[0] / (kF * kD);   // 16384
    interact_kernel<<<B, 256, 0, stream>>>(X, Wq, Wk, Wv, Wr, out);
}

// Round 2
// 278.887 us; speedup vs baseline: 1.8692x; 1.8692x over previous
//
#include <hip/hip_runtime.h>

// InteractLayer via bf16 MFMA (16x16x32). B=16384 batches, F=32, D=64, H=64 (2 heads x 32).
// Pre-kernel: W (4x [64x64] f32) -> bf16 transposed Wt[e][d] in d_ws.
// Main: block = 1 batch, 4 waves. Phase1: wave w computes projection w (Q,K,V,R),
// V stored transposed in LDS. Phase2: wave=(head,rowblock), QK^T + in-register softmax.
// Phase3: PV + residual + relu. All matmul layouts per verified gfx950 fragment maps.

constexpr int kF = 32, kD = 64, kH = 64;

constexpr int XS = 72;   // s_x row stride (bf16): 144B rows, 16B aligned, 2-way banks
constexpr int QS = 72;   // s_q / s_k / s_r row stride
constexpr int VS = 40;   // s_vt row stride (80B rows, 16B aligned)
constexpr int PS = 40;   // s_p row stride

using short8  = __attribute__((ext_vector_type(8))) short;
using float4v = __attribute__((ext_vector_type(4))) float;

__device__ __forceinline__ unsigned short f2bf(float x) {
    unsigned u = __float_as_uint(x);
    u += 0x7FFF + ((u >> 16) & 1);          // round-to-nearest-even
    return (unsigned short)(u >> 16);
}
__device__ __forceinline__ float bf2f(unsigned short b) {
    return __uint_as_float((unsigned)b << 16);
}

__global__ void wprep_kernel(const float* __restrict__ Wq, const float* __restrict__ Wk,
                             const float* __restrict__ Wv, const float* __restrict__ Wr,
                             unsigned short* __restrict__ wt) {
    const int m = blockIdx.x;               // 0..3 : Q,K,V,R
    const float* __restrict__ W = (m == 0) ? Wq : (m == 1) ? Wk : (m == 2) ? Wv : Wr;
    for (int i = threadIdx.x; i < kD * kH; i += blockDim.x) {
        const int e = i >> 6, d = i & 63;
        wt[m * kD * kH + e * kD + d] = f2bf(W[d * kH + e]);   // transposed: Wt[e][d]
    }
}

__global__ __launch_bounds__(256)
void interact_mfma(const float* __restrict__ X, const unsigned short* __restrict__ Wt,
                   float* __restrict__ out)
{
    __shared__ __align__(16) unsigned short s_x [kF * XS];
    __shared__ __align__(16) unsigned short s_q [kF * QS];
    __shared__ __align__(16) unsigned short s_k [kF * QS];
    __shared__ __align__(16) unsigned short s_r [kF * QS];
    __shared__ __align__(16) unsigned short s_vt[kH * VS];      // Vt[e][token]
    __shared__ __align__(16) unsigned short s_p [2 * kF * PS];  // P[h][q][k], unnormalized exp

    const int t    = threadIdx.x;
    const int w    = t >> 6;        // wave 0..3
    const int lane = t & 63;
    const int quad = lane >> 4;     // 0..3
    const int l    = lane & 15;
    const int b    = blockIdx.x;

    // ---- W B-fragments for projection (wave w owns matrix w), from global Wt ----
    // B[k=d][n=e] frag: lane holds Wt[e = 16*nt + l][d = 32*ks + quad*8 + j]
    short8 bfrag[4][2];
    {
        const unsigned short* __restrict__ wtm = Wt + w * (kD * kH);
        #pragma unroll
        for (int nt = 0; nt < 4; ++nt)
            #pragma unroll
            for (int ks = 0; ks < 2; ++ks)
                bfrag[nt][ks] =
                    *reinterpret_cast<const short8*>(wtm + (16 * nt + l) * kD + 32 * ks + quad * 8);
    }

    // ---- stage X -> LDS (bf16) ----
    const float* __restrict__ Xb = X + (size_t)b * (kF * kD);
    #pragma unroll
    for (int i = 0; i < 2; ++i) {
        const int idx = i * 256 + t;          // 0..511 float4s
        const int f = idx >> 4, c = idx & 15;
        const float4 v = reinterpret_cast<const float4*>(Xb)[idx];
        ushort4 pk;
        pk.x = f2bf(v.x); pk.y = f2bf(v.y); pk.z = f2bf(v.z); pk.w = f2bf(v.w);
        *reinterpret_cast<ushort4*>(&s_x[f * XS + c * 4]) = pk;
    }
    __syncthreads();

    // ---- phase 1: projection w: Out[32x64] = X[32x64] @ W_w[64x64] ----
    {
        float4v acc[2][4];
        #pragma unroll
        for (int mt = 0; mt < 2; ++mt)
            #pragma unroll
            for (int nt = 0; nt < 4; ++nt)
                acc[mt][nt] = (float4v){0.f, 0.f, 0.f, 0.f};

        short8 afrag[2][2];   // A[m = 16*mt + l][k = 32*ks + quad*8 + j]
        #pragma unroll
        for (int mt = 0; mt < 2; ++mt)
            #pragma unroll
            for (int ks = 0; ks < 2; ++ks)
                afrag[mt][ks] =
                    *reinterpret_cast<const short8*>(&s_x[(16 * mt + l) * XS + 32 * ks + quad * 8]);

        #pragma unroll
        for (int mt = 0; mt < 2; ++mt)
            #pragma unroll
            for (int nt = 0; nt < 4; ++nt) {
                acc[mt][nt] = __builtin_amdgcn_mfma_f32_16x16x32_bf16(
                    afrag[mt][0], bfrag[nt][0], acc[mt][nt], 0, 0, 0);
                acc[mt][nt] = __builtin_amdgcn_mfma_f32_16x16x32_bf16(
                    afrag[mt][1], bfrag[nt][1], acc[mt][nt], 0, 0, 0);
            }

        // C/D layout: element (reg r, lane) = Out[16*mt + quad*4 + r][16*nt + l]
        if (w == 2) {
            // V: store transposed Vt[e][token]
            #pragma unroll
            for (int mt = 0; mt < 2; ++mt)
                #pragma unroll
                for (int nt = 0; nt < 4; ++nt)
                    #pragma unroll
                    for (int r = 0; r < 4; ++r)
                        s_vt[(16 * nt + l) * VS + 16 * mt + quad * 4 + r] = f2bf(acc[mt][nt][r]);
        } else {
            unsigned short* __restrict__ dst = (w == 0) ? s_q : (w == 1) ? s_k : s_r;
            #pragma unroll
            for (int mt = 0; mt < 2; ++mt)
                #pragma unroll
                for (int nt = 0; nt < 4; ++nt)
                    #pragma unroll
                    for (int r = 0; r < 4; ++r)
                        dst[(16 * mt + quad * 4 + r) * QS + 16 * nt + l] = f2bf(acc[mt][nt][r]);
        }
    }
    __syncthreads();

    // ---- phase 2: scores + in-register softmax. wave -> (head h, row-block mt) ----
    const int h  = w >> 1;
    const int mt = w & 1;
    float inv[4];
    {
        const short8 qa =
            *reinterpret_cast<const short8*>(&s_q[(16 * mt + l) * QS + 32 * h + quad * 8]);
        const short8 kb0 =
            *reinterpret_cast<const short8*>(&s_k[(l) * QS + 32 * h + quad * 8]);
        const short8 kb1 =
            *reinterpret_cast<const short8*>(&s_k[(16 + l) * QS + 32 * h + quad * 8]);

        float4v s0 = (float4v){0.f, 0.f, 0.f, 0.f};
        float4v s1 = (float4v){0.f, 0.f, 0.f, 0.f};
        s0 = __builtin_amdgcn_mfma_f32_16x16x32_bf16(qa, kb0, s0, 0, 0, 0);
        s1 = __builtin_amdgcn_mfma_f32_16x16x32_bf16(qa, kb1, s1, 0, 0, 0);

        // row (16*mt + quad*4 + r): its 32 scores live in this quad's 16 lanes x {s0,s1}
        #pragma unroll
        for (int r = 0; r < 4; ++r) {
            float m = fmaxf(s0[r], s1[r]);
            #pragma unroll
            for (int d = 1; d < 16; d <<= 1) m = fmaxf(m, __shfl_xor(m, d));
            const float e0 = __expf(s0[r] - m);
            const float e1 = __expf(s1[r] - m);
            float sum = e0 + e1;
            #pragma unroll
            for (int d = 1; d < 16; d <<= 1) sum += __shfl_xor(sum, d);
            inv[r] = 1.0f / sum;   // normalization deferred to after PV
            const int row = 16 * mt + quad * 4 + r;
            s_p[(h * kF + row) * PS + l]      = f2bf(e0);
            s_p[(h * kF + row) * PS + 16 + l] = f2bf(e1);
        }
    }
    __syncthreads();

    // ---- phase 3: O_h = P_h @ V_h, + residual, relu, store ----
    {
        const short8 pa =
            *reinterpret_cast<const short8*>(&s_p[(h * kF + 16 * mt + l) * PS + quad * 8]);
        const short8 vb0 =
            *reinterpret_cast<const short8*>(&s_vt[(32 * h + l) * VS + quad * 8]);
        const short8 vb1 =
            *reinterpret_cast<const short8*>(&s_vt[(32 * h + 16 + l) * VS + quad * 8]);

        float4v o0 = (float4v){0.f, 0.f, 0.f, 0.f};
        float4v o1 = (float4v){0.f, 0.f, 0.f, 0.f};
        o0 = __builtin_amdgcn_mfma_f32_16x16x32_bf16(pa, vb0, o0, 0, 0, 0);
        o1 = __builtin_amdgcn_mfma_f32_16x16x32_bf16(pa, vb1, o1, 0, 0, 0);

        float* __restrict__ Ob = out + (size_t)b * (kF * kH);
        #pragma unroll
        for (int r = 0; r < 4; ++r) {
            const int f = 16 * mt + quad * 4 + r;
            const float rv0 = bf2f(s_r[f * QS + 32 * h + l]);
            const float rv1 = bf2f(s_r[f * QS + 32 * h + 16 + l]);
            Ob[f * kH + 32 * h + l]      = fmaxf(o0[r] * inv[r] + rv0, 0.0f);
            Ob[f * kH + 32 * h + 16 + l] = fmaxf(o1[r] * inv[r] + rv1, 0.0f);
        }
    }
}

extern "C" void kernel_launch(void* const* d_in, const int* in_sizes, int n_in,
                              void* d_out, int out_size, void* d_ws, size_t ws_size,
                              hipStream_t stream) {
    const float* X  = (const float*)d_in[0];
    const float* Wq = (const float*)d_in[1];
    const float* Wk = (const float*)d_in[2];
    const float* Wv = (const float*)d_in[3];
    const float* Wr = (const float*)d_in[4];
    float* out = (float*)d_out;
    unsigned short* wt = (unsigned short*)d_ws;   // 4*64*64*2 = 32 KiB

    wprep_kernel<<<4, 256, 0, stream>>>(Wq, Wk, Wv, Wr, wt);

    const int B = in_sizes[0] / (kF * kD);        // 16384
    interact_mfma<<<B, 256, 0, stream>>>(X, wt, out);
}